// Round 5
// baseline (303.385 us; speedup 1.0000x reference)
//
#include <hip/hip_runtime.h>
#include <hip/hip_bf16.h>
#include <stdint.h>

#define D 512
#define N 8192

typedef __attribute__((ext_vector_type(8))) short short8;
typedef __attribute__((ext_vector_type(4))) float f32x4;

static __device__ __forceinline__ unsigned short f2bf(float f) {
  unsigned int u = __builtin_bit_cast(unsigned int, f);
  u += 0x7fffu + ((u >> 16) & 1u);
  return (unsigned short)(u >> 16);
}
static __device__ __forceinline__ float bf2f(unsigned short s) {
  unsigned int u = ((unsigned int)s) << 16;
  return __builtin_bit_cast(float, u);
}

typedef const __attribute__((address_space(1))) unsigned int* gas_ptr;
typedef __attribute__((address_space(3))) unsigned int* las_ptr;
static __device__ __forceinline__ void gload_lds16(const void* g, void* l) {
  __builtin_amdgcn_global_load_lds((gas_ptr)g, (las_ptr)l, 16, 0, 0);
}

// ---------------- cast kernels ----------------
__global__ void cast_z_k(const float* __restrict__ z, unsigned short* __restrict__ zb) {
  int i = blockIdx.x * 256 + threadIdx.x;
  const int n4 = N * D / 4;
  for (; i < n4; i += gridDim.x * 256) {
    float4 v = ((const float4*)z)[i];
    ushort4 o = { f2bf(v.x), f2bf(v.y), f2bf(v.z), f2bf(v.w) };
    ((ushort4*)zb)[i] = o;
  }
}

__global__ void cast_w_k(const float* __restrict__ Wq, const float* __restrict__ Wk,
                         const float* __restrict__ Wv, const float* __restrict__ bq,
                         const float* __restrict__ bk, const float* __restrict__ bv,
                         unsigned short* __restrict__ wb, float* __restrict__ bqkv) {
  const float scale = 0.044194173824159216f;  // 512^-0.5 folded into Wq,bq
  int i = blockIdx.x * 256 + threadIdx.x;
  const int per = D * D / 4;
  if (i < 3 * per) {
    int sec = i / per;
    int w4 = i - sec * per;
    const float* W = sec == 0 ? Wq : (sec == 1 ? Wk : Wv);
    float s = sec == 0 ? scale : 1.0f;
    float4 v = ((const float4*)W)[w4];
    ushort4 o = { f2bf(v.x * s), f2bf(v.y * s), f2bf(v.z * s), f2bf(v.w * s) };
    ((ushort4*)wb)[sec * per + w4] = o;
  }
  if (i < 3 * D) {
    int sec = i >> 9, j = i & (D - 1);
    const float* b = sec == 0 ? bq : (sec == 1 ? bk : bv);
    bqkv[i] = b[j] * (sec == 0 ? scale : 1.0f);
  }
}

// ============ 128x128 NT-GEMM engine: BK=64, 512 thr (8 waves 2Mx4N),
// ============ 4-buffer LDS ring, 1 barrier/K-tile, counted vmcnt(4).
// Per K-tile phase: [ds-reads(buf kt&3); stage tile kt+2; vmcnt(4); barrier;
//                    lgkmcnt(0); setprio1; 16 MFMA; setprio0]
// Counted-wait invariant: vmcnt(4) guarantees tile kt+1 landed ONLY when tile
// kt+2 was just staged (newest-4 = kt+2). At the tail (no stage issued) the
// newest-4 ARE tile kt+1 -> must drain vmcnt(0) instead. (R4 bug: raced the
// final K-tile of every GEMM.)
// EPI 0: qkv proj (bias; q/k row-major, v transposed)
// EPI 1: P = exp(S) nt-store + per-tile rowsum partials (deterministic)
// EPI 3: split-K PV partial (sp<3 -> bf16 nt; sp==3 -> f32 to d_out)
template <int EPI>
__global__ __launch_bounds__(512) void mm128_ring(
    const unsigned short* __restrict__ A, int lda,
    const unsigned short* __restrict__ B, int ldb,
    const float* __restrict__ bias,
    unsigned short* __restrict__ o0, unsigned short* __restrict__ o1,
    unsigned short* __restrict__ o2,
    float* __restrict__ lpart, float* __restrict__ outF) {
  __shared__ unsigned short Ash[4][128 * 64];
  __shared__ unsigned short Bsh[4][128 * 64];

  const int t = threadIdx.x;
  const int w = t >> 6, lane = t & 63;
  const int wr = w >> 2, wc = w & 3;
  const int l15 = lane & 15, lhi = lane >> 4, lx = lane & 7;
  const int bid = blockIdx.x;

  int tm, tn, kt0 = 0, nkt, sp = 0;
  if constexpr (EPI == 0) {
    const int swz = (bid & 7) * 96 + (bid >> 3);   // 768 WGs
    tm = swz / 12; tn = swz - tm * 12; nkt = 8;
  } else if constexpr (EPI == 1) {
    const int swz = (bid & 7) * 512 + (bid >> 3);  // 4096 WGs
    tm = swz >> 6; tn = swz & 63; nkt = 8;
  } else {
    const int swz = (bid & 7) * 128 + (bid >> 3);  // 1024 WGs
    sp = swz >> 8;
    const int idx = swz & 255;
    tm = idx >> 2; tn = idx & 3;
    kt0 = sp * 32; nkt = 32;
  }
  const int row0 = tm * 128, col0 = tn * 128;

  // staging: thread t covers row sr=t>>3 of each 64-row half, 16B slot t&7;
  // source col pre-swizzled so LDS stays linear; read side XORs (row&7).
  const int sr = t >> 3;
  const int sc = ((t & 7) ^ (sr & 7)) * 8;
  const unsigned short* Ab = A + (size_t)(row0 + sr) * lda + sc;
  const unsigned short* Bb = B + (size_t)(col0 + sr) * ldb + sc;
  const int dst = t * 8;

  const int arow = (wr * 64 + l15) * 64;
  const int brow = (wc * 32 + l15) * 64;
  const int sl0 = ((0 + lhi) ^ lx) * 8;
  const int sl1 = ((4 + lhi) ^ lx) * 8;

  f32x4 acc[4][2] = {};

  auto stage = [&](int buf, int kt) {
    const unsigned short* a = Ab + (size_t)(kt0 + kt) * 64;
    const unsigned short* b = Bb + (size_t)(kt0 + kt) * 64;
    gload_lds16(a, &Ash[buf][dst]);
    gload_lds16(a + (size_t)64 * lda, &Ash[buf][4096 + dst]);
    gload_lds16(b, &Bsh[buf][dst]);
    gload_lds16(b + (size_t)64 * ldb, &Bsh[buf][4096 + dst]);
  };

  // prologue: tiles 0,1 in flight; vmcnt(4)+bar => tile 0 ready for phase 0
  stage(0, 0);
  stage(1, 1);
  asm volatile("s_waitcnt vmcnt(4)" ::: "memory");
  __builtin_amdgcn_s_barrier();

  for (int kt = 0; kt < nkt; ++kt) {
    const int kb = kt & 3;
    short8 af[4][2], bg[2][2];
#pragma unroll
    for (int fm = 0; fm < 4; ++fm) {
      const unsigned short* p = &Ash[kb][arow + fm * 1024];
      af[fm][0] = *(const short8*)(p + sl0);
      af[fm][1] = *(const short8*)(p + sl1);
    }
#pragma unroll
    for (int fn = 0; fn < 2; ++fn) {
      const unsigned short* p = &Bsh[kb][brow + fn * 1024];
      bg[fn][0] = *(const short8*)(p + sl0);
      bg[fn][1] = *(const short8*)(p + sl1);
    }
    if (kt + 2 < nkt) {
      stage((kt + 2) & 3, kt + 2);
      asm volatile("s_waitcnt vmcnt(4)" ::: "memory");  // tile kt+1 landed (newest-4 = kt+2)
    } else {
      asm volatile("s_waitcnt vmcnt(0)" ::: "memory");  // tail: drain (newest-4 = kt+1)
    }
    __builtin_amdgcn_s_barrier();
    asm volatile("s_waitcnt lgkmcnt(0)" ::: "memory");
    __builtin_amdgcn_sched_barrier(0);
    __builtin_amdgcn_s_setprio(1);
#pragma unroll
    for (int ks = 0; ks < 2; ++ks)
#pragma unroll
      for (int fm = 0; fm < 4; ++fm)
#pragma unroll
        for (int fn = 0; fn < 2; ++fn)
          acc[fm][fn] = __builtin_amdgcn_mfma_f32_16x16x32_bf16(
              af[fm][ks], bg[fn][ks], acc[fm][fn], 0, 0, 0);
    __builtin_amdgcn_s_setprio(0);
  }

  // ---------------- epilogues ----------------
  if constexpr (EPI == 0) {
    const int sec = tn >> 2;  // 0=q 1=k 2=v (uniform per WG; 128-col tile in 512-col section)
#pragma unroll
    for (int fn = 0; fn < 2; ++fn) {
      const int c = col0 + wc * 32 + fn * 16 + l15;
      const int cj = c & (D - 1);
      const float bb = bias[c];
#pragma unroll
      for (int fm = 0; fm < 4; ++fm) {
        const int r = row0 + wr * 64 + fm * 16 + lhi * 4;
        f32x4 v = acc[fm][fn];
        if (sec == 0) {
#pragma unroll
          for (int g = 0; g < 4; ++g) o0[(size_t)(r + g) * D + cj] = f2bf(v[g] + bb);
        } else if (sec == 1) {
#pragma unroll
          for (int g = 0; g < 4; ++g) o1[(size_t)(r + g) * D + cj] = f2bf(v[g] + bb);
        } else {  // v -> transposed vT[d][m], 4 consecutive m packed into 8B
          ushort4 o = { f2bf(v[0] + bb), f2bf(v[1] + bb), f2bf(v[2] + bb), f2bf(v[3] + bb) };
          *(ushort4*)(o2 + (size_t)cj * N + r) = o;
        }
      }
    }
  }

  if constexpr (EPI == 1) {
    float rs[4][4];
#pragma unroll
    for (int fm = 0; fm < 4; ++fm)
#pragma unroll
      for (int g = 0; g < 4; ++g) rs[fm][g] = 0.f;
#pragma unroll
    for (int fn = 0; fn < 2; ++fn) {
      const int c = col0 + wc * 32 + fn * 16 + l15;
#pragma unroll
      for (int fm = 0; fm < 4; ++fm) {
        const int r = row0 + wr * 64 + fm * 16 + lhi * 4;
        f32x4 v = acc[fm][fn];
#pragma unroll
        for (int g = 0; g < 4; ++g) {
          unsigned short us = f2bf(__expf(v[g]));
          __builtin_nontemporal_store(us, &o0[(size_t)(r + g) * N + c]);
          rs[fm][g] += bf2f(us);  // sum the rounded value (numer/denom consistency)
        }
      }
    }
    // reduce over the 16 col-lanes, then cross-wave (wc) via LDS
#pragma unroll
    for (int fm = 0; fm < 4; ++fm)
#pragma unroll
      for (int g = 0; g < 4; ++g) {
        float s = rs[fm][g];
        s += __shfl_xor(s, 1);
        s += __shfl_xor(s, 2);
        s += __shfl_xor(s, 4);
        s += __shfl_xor(s, 8);
        rs[fm][g] = s;
      }
    __builtin_amdgcn_s_barrier();                 // all waves past last LDS reads
    float* lred = (float*)&Ash[0][0];             // [4 wc][128 rows]
    if (l15 == 0) {
#pragma unroll
      for (int fm = 0; fm < 4; ++fm)
#pragma unroll
        for (int g = 0; g < 4; ++g)
          lred[wc * 128 + wr * 64 + fm * 16 + lhi * 4 + g] = rs[fm][g];
    }
    __syncthreads();
    if (t < 128) {
      float s = lred[t] + lred[128 + t] + lred[256 + t] + lred[384 + t];
      lpart[(size_t)tn * N + row0 + t] = s;       // slot = tn (deterministic)
    }
  }

  if constexpr (EPI == 3) {
    if (sp < 3) {
      unsigned short* op = o0 + (size_t)sp * ((size_t)N * D);
#pragma unroll
      for (int fn = 0; fn < 2; ++fn) {
        const int c = col0 + wc * 32 + fn * 16 + l15;
#pragma unroll
        for (int fm = 0; fm < 4; ++fm) {
          const int r = row0 + wr * 64 + fm * 16 + lhi * 4;
          f32x4 v = acc[fm][fn];
#pragma unroll
          for (int g = 0; g < 4; ++g)
            __builtin_nontemporal_store(f2bf(v[g]), &op[(size_t)(r + g) * D + c]);
        }
      }
    } else {  // 4th partial goes f32 straight into d_out; reduce_k does RMW
#pragma unroll
      for (int fn = 0; fn < 2; ++fn) {
        const int c = col0 + wc * 32 + fn * 16 + l15;
#pragma unroll
        for (int fm = 0; fm < 4; ++fm) {
          const int r = row0 + wr * 64 + fm * 16 + lhi * 4;
          f32x4 v = acc[fm][fn];
#pragma unroll
          for (int g = 0; g < 4; ++g)
            __builtin_nontemporal_store(v[g], &outF[(size_t)(r + g) * D + c]);
        }
      }
    }
  }
}

// linv[m] = 1 / sum_{64 slots} lpart[slot][m]
__global__ void linv_k(const float* __restrict__ lpart, float* __restrict__ linv) {
  const int m = blockIdx.x * 256 + threadIdx.x;
  float s = 0.f;
  for (int i = 0; i < 64; ++i) s += lpart[(size_t)i * N + m];
  linv[m] = 1.0f / s;
}

// out[m][d] = linv[m] * (sum_{s<3} Opart_bf16[s][m][d] + out_f32[m][d])
__global__ void reduce_k(const unsigned short* __restrict__ Opart,
                         const float* __restrict__ linv, float* __restrict__ out) {
  const int i = blockIdx.x * 256 + threadIdx.x;  // over N*D/4
  const int m = i >> 7;                           // 128 float4 per row
  const float li = linv[m];
  const size_t nd = (size_t)N * D;
  ushort4 a = ((const ushort4*)Opart)[i];
  ushort4 b = ((const ushort4*)(Opart + nd))[i];
  ushort4 c = ((const ushort4*)(Opart + 2 * nd))[i];
  float4 o = ((float4*)out)[i];
  o.x = (bf2f(a.x) + bf2f(b.x) + bf2f(c.x) + o.x) * li;
  o.y = (bf2f(a.y) + bf2f(b.y) + bf2f(c.y) + o.y) * li;
  o.z = (bf2f(a.z) + bf2f(b.z) + bf2f(c.z) + o.z) * li;
  o.w = (bf2f(a.w) + bf2f(b.w) + bf2f(c.w) + o.w) * li;
  ((float4*)out)[i] = o;
}

extern "C" void kernel_launch(void* const* d_in, const int* in_sizes, int n_in,
                              void* d_out, int out_size, void* d_ws, size_t ws_size,
                              hipStream_t stream) {
  const float* z  = (const float*)d_in[0];
  const float* Wq = (const float*)d_in[1];
  const float* bq = (const float*)d_in[2];
  const float* Wk = (const float*)d_in[3];
  const float* bk = (const float*)d_in[4];
  const float* Wv = (const float*)d_in[5];
  const float* bv = (const float*)d_in[6];
  float* out = (float*)d_out;

  char* ws = (char*)d_ws;
  unsigned short* zb = (unsigned short*)(ws + 0);          //  8 MB  z bf16
  unsigned short* qb = (unsigned short*)(ws + 8388608);    //  8 MB  q bf16 (scaled)
  unsigned short* kb = (unsigned short*)(ws + 16777216);   //  8 MB  k bf16
  unsigned short* vT = (unsigned short*)(ws + 25165824);   //  8 MB  v^T bf16 [512][8192]
  unsigned short* wb = (unsigned short*)(ws + 33554432);   //  1.5MB W_qkv bf16 [1536][512]
  float* linv       = (float*)(ws + 33554432);             //  32 KB (overlays wb; wb dead after proj)
  float* bqkv       = (float*)(ws + 35127296);             //  6 KB  biases f32
  float* lpart      = (float*)(ws + 35133440);             //  2 MB  rowsum partials [64][8192]
  unsigned short* P = (unsigned short*)(ws + 39327744);    // 128 MB P bf16 [8192][8192]
  // Opart partials 0..2 overlay zb/qb/kb (dead by PV); partial 3 -> d_out f32
  unsigned short* Opart = (unsigned short*)(ws + 0);

  cast_z_k<<<dim3(2048), dim3(256), 0, stream>>>(z, zb);
  cast_w_k<<<dim3(768), dim3(256), 0, stream>>>(Wq, Wk, Wv, bq, bk, bv, wb, bqkv);

  // qkv projection: [8192x1536] = zb @ wb^T (+bias)
  mm128_ring<0><<<dim3(768), dim3(512), 0, stream>>>(
      zb, D, wb, D, bqkv, qb, kb, vT, (float*)nullptr, (float*)nullptr);

  // scores+exp: P = exp(qb @ kb^T) + rowsum partials
  mm128_ring<1><<<dim3(4096), dim3(512), 0, stream>>>(
      qb, D, kb, D, (const float*)nullptr, P, (unsigned short*)nullptr,
      (unsigned short*)nullptr, lpart, (float*)nullptr);

  // row-sum inverse
  linv_k<<<dim3(32), dim3(256), 0, stream>>>(lpart, linv);

  // split-K PV (4 splits x K=2048): partials 0-2 bf16, partial 3 f32 -> d_out
  mm128_ring<3><<<dim3(1024), dim3(512), 0, stream>>>(
      P, N, vT, N, (const float*)nullptr, Opart, (unsigned short*)nullptr,
      (unsigned short*)nullptr, (float*)nullptr, out);

  // out = linv * (sum partials + d_out partial)
  reduce_k<<<dim3(4096), dim3(256), 0, stream>>>(Opart, linv, out);
}

// Round 6
// 226.814 us; speedup vs baseline: 1.3376x; 1.3376x over previous
//
#include <hip/hip_runtime.h>
#include <hip/hip_bf16.h>
#include <stdint.h>

#define D 512
#define N 8192

typedef __attribute__((ext_vector_type(8))) short short8;
typedef __attribute__((ext_vector_type(4))) float f32x4;

static __device__ __forceinline__ unsigned short f2bf(float f) {
  unsigned int u = __builtin_bit_cast(unsigned int, f);
  u += 0x7fffu + ((u >> 16) & 1u);
  return (unsigned short)(u >> 16);
}
static __device__ __forceinline__ float bf2f(unsigned short s) {
  unsigned int u = ((unsigned int)s) << 16;
  return __builtin_bit_cast(float, u);
}

typedef const __attribute__((address_space(1))) unsigned int* gas_ptr;
typedef __attribute__((address_space(3))) unsigned int* las_ptr;
static __device__ __forceinline__ void gload_lds16(const void* g, void* l) {
  __builtin_amdgcn_global_load_lds((gas_ptr)g, (las_ptr)l, 16, 0, 0);
}

// ---------------- cast kernels ----------------
__global__ void cast_z_k(const float* __restrict__ z, unsigned short* __restrict__ zb) {
  int i = blockIdx.x * 256 + threadIdx.x;
  const int n4 = N * D / 4;
  for (; i < n4; i += gridDim.x * 256) {
    float4 v = ((const float4*)z)[i];
    ushort4 o = { f2bf(v.x), f2bf(v.y), f2bf(v.z), f2bf(v.w) };
    ((ushort4*)zb)[i] = o;
  }
}

__global__ void cast_w_k(const float* __restrict__ Wq, const float* __restrict__ Wk,
                         const float* __restrict__ Wv, const float* __restrict__ bq,
                         const float* __restrict__ bk, const float* __restrict__ bv,
                         unsigned short* __restrict__ wb, float* __restrict__ bqkv) {
  const float scale = 0.044194173824159216f;  // 512^-0.5 folded into Wq,bq
  int i = blockIdx.x * 256 + threadIdx.x;
  const int per = D * D / 4;
  if (i < 3 * per) {
    int sec = i / per;
    int w4 = i - sec * per;
    const float* W = sec == 0 ? Wq : (sec == 1 ? Wk : Wv);
    float s = sec == 0 ? scale : 1.0f;
    float4 v = ((const float4*)W)[w4];
    ushort4 o = { f2bf(v.x * s), f2bf(v.y * s), f2bf(v.z * s), f2bf(v.w * s) };
    ((ushort4*)wb)[sec * per + w4] = o;
  }
  if (i < 3 * D) {
    int sec = i >> 9, j = i & (D - 1);
    const float* b = sec == 0 ? bq : (sec == 1 ? bk : bv);
    bqkv[i] = b[j] * (sec == 0 ? scale : 1.0f);
  }
}

// ---------------- proj: NT GEMM, 128x128 tile, BK=64, 4 waves, dbuf 2-phase ----------------
// (R1/R3-proven; bias add, write q/k bf16 row-major, v transposed)
__global__ __launch_bounds__(256) void proj_qkv(
    const unsigned short* __restrict__ A,
    const unsigned short* __restrict__ B,
    const float* __restrict__ bias,
    unsigned short* __restrict__ o0, unsigned short* __restrict__ o1,
    unsigned short* __restrict__ o2) {
  __shared__ unsigned short Ash[2][128 * 64];
  __shared__ unsigned short Bsh[2][128 * 64];

  const int t = threadIdx.x;
  const int w = t >> 6, lane = t & 63;
  const int bid = blockIdx.x;
  const int swz = (bid & 7) * 96 + (bid >> 3);  // 768 WGs, bijective
  const int tm = swz / 12, tn = swz - tm * 12;
  const int row0 = tm * 128, col0 = tn * 128;

  const int srow = t >> 3;
  const int scol = ((t & 7) ^ ((t >> 3) & 7)) * 8;
  const unsigned short* Ab = A + (size_t)(row0 + srow) * D + scol;
  const unsigned short* Bb = B + (size_t)(col0 + srow) * D + scol;
  const int ldsbase = (w * 64) * 8;

  const int l15 = lane & 15, lhi = lane >> 4, lx = lane & 7;
  const int wr = w >> 1, wc = w & 1;
  const int arow = (wr * 64 + l15) * 64;
  const int brow = (wc * 64 + l15) * 64;
  const int ko0 = ((0 + lhi) ^ lx) * 8;
  const int ko1 = ((4 + lhi) ^ lx) * 8;

  f32x4 acc[4][4] = {};

  auto stage = [&](int buf, int k0) {
    const unsigned short* a = Ab + k0;
    const unsigned short* b = Bb + k0;
    unsigned short* la = &Ash[buf][ldsbase];
    unsigned short* lb = &Bsh[buf][ldsbase];
#pragma unroll
    for (int i = 0; i < 4; ++i) {
      gload_lds16(a + (size_t)(i * 32) * D, la + i * 2048);
      gload_lds16(b + (size_t)(i * 32) * D, lb + i * 2048);
    }
  };

  stage(0, 0);
  asm volatile("s_waitcnt vmcnt(0)" ::: "memory");
  __syncthreads();
  int cur = 0;
  for (int kt = 0; kt < 8; ++kt) {
    if (kt + 1 < 8) stage(cur ^ 1, (kt + 1) * 64);
    const unsigned short* As = Ash[cur];
    const unsigned short* Bs = Bsh[cur];
#pragma unroll
    for (int ks = 0; ks < 2; ++ks) {
      const int ko = ks ? ko1 : ko0;
      short8 af[4], bg[4];
#pragma unroll
      for (int rf = 0; rf < 4; ++rf)
        af[rf] = *(const short8*)(As + arow + rf * (16 * 64) + ko);
#pragma unroll
      for (int cf = 0; cf < 4; ++cf)
        bg[cf] = *(const short8*)(Bs + brow + cf * (16 * 64) + ko);
#pragma unroll
      for (int rf = 0; rf < 4; ++rf)
#pragma unroll
        for (int cf = 0; cf < 4; ++cf)
          acc[rf][cf] = __builtin_amdgcn_mfma_f32_16x16x32_bf16(af[rf], bg[cf], acc[rf][cf], 0, 0, 0);
    }
    asm volatile("s_waitcnt vmcnt(0)" ::: "memory");
    __syncthreads();
    cur ^= 1;
  }

  const int r0g = row0 + wr * 64;
  const int c0g = col0 + wc * 64;
  const int sec = col0 >> 9;  // 0=q 1=k 2=v
#pragma unroll
  for (int cf = 0; cf < 4; ++cf) {
    const int c = c0g + cf * 16 + l15;
    const int cj = c & (D - 1);
    const float bb = bias[c];
#pragma unroll
    for (int rf = 0; rf < 4; ++rf) {
      const int r = r0g + rf * 16 + lhi * 4;
      f32x4 v = acc[rf][cf];
      if (sec == 0) {
#pragma unroll
        for (int g = 0; g < 4; ++g) o0[(size_t)(r + g) * D + cj] = f2bf(v[g] + bb);
      } else if (sec == 1) {
#pragma unroll
        for (int g = 0; g < 4; ++g) o1[(size_t)(r + g) * D + cj] = f2bf(v[g] + bb);
      } else {
        ushort4 o = { f2bf(v[0] + bb), f2bf(v[1] + bb), f2bf(v[2] + bb), f2bf(v[3] + bb) };
        *(ushort4*)(o2 + (size_t)cj * N + r) = o;
      }
    }
  }
}

// ======== shared 8-phase 256x256 macros (R3-verified schedule) ========
#define STAGE8(buf, kt, LDB)                                                \
  do {                                                                      \
    const unsigned short* a_ = Ab + (size_t)(kt) * 64;                      \
    const unsigned short* b_ = Bb + (size_t)(kt) * 64;                      \
    unsigned short* la_ = &Ash[buf][0];                                     \
    unsigned short* lb_ = &Bsh[buf][0];                                     \
    gload_lds16(a_, la_ + ldst);                                            \
    gload_lds16(a_ + (size_t)64 * (LDB), la_ + 4096 + ldst);                \
    gload_lds16(a_ + (size_t)128 * (LDB), la_ + 8192 + ldst);               \
    gload_lds16(a_ + (size_t)192 * (LDB), la_ + 12288 + ldst);              \
    gload_lds16(b_, lb_ + ldst);                                            \
    gload_lds16(b_ + (size_t)64 * (LDB), lb_ + 4096 + ldst);                \
    gload_lds16(b_ + (size_t)128 * (LDB), lb_ + 8192 + ldst);               \
    gload_lds16(b_ + (size_t)192 * (LDB), lb_ + 12288 + ldst);              \
  } while (0)

#define RDA(kk, mh)                                                          \
  do {                                                                       \
    _Pragma("unroll") for (int fm = 0; fm < 4; ++fm) {                       \
      const unsigned short* p_ = &Ash[kk][aRowB + (mh) * 4096 + fm * 1024];  \
      af[fm][0] = *(const short8*)(p_ + sl0);                                \
      af[fm][1] = *(const short8*)(p_ + sl1);                                \
    }                                                                        \
  } while (0)

#define RDB(kk, nh)                                                          \
  do {                                                                       \
    _Pragma("unroll") for (int fn = 0; fn < 2; ++fn) {                       \
      const unsigned short* p_ = &Bsh[kk][bRowB + (nh) * 2048 + fn * 1024];  \
      bf[fn][0] = *(const short8*)(p_ + sl0);                                \
      bf[fn][1] = *(const short8*)(p_ + sl1);                                \
    }                                                                        \
  } while (0)

#define MMA(mh, nh)                                                          \
  do {                                                                       \
    __builtin_amdgcn_s_setprio(1);                                           \
    _Pragma("unroll") for (int ks = 0; ks < 2; ++ks)                         \
      _Pragma("unroll") for (int fm = 0; fm < 4; ++fm)                       \
        _Pragma("unroll") for (int fn = 0; fn < 2; ++fn)                     \
          acc[(mh) * 4 + fm][(nh) * 2 + fn] =                                \
              __builtin_amdgcn_mfma_f32_16x16x32_bf16(                       \
                  af[fm][ks], bf[fn][ks], acc[(mh) * 4 + fm][(nh) * 2 + fn], \
                  0, 0, 0);                                                  \
    __builtin_amdgcn_s_setprio(0);                                           \
  } while (0)

#define BARLG()                                         \
  do {                                                  \
    __builtin_amdgcn_s_barrier();                       \
    asm volatile("s_waitcnt lgkmcnt(0)" ::: "memory");  \
    __builtin_amdgcn_sched_barrier(0);                  \
  } while (0)

#define VMDRAIN() asm volatile("s_waitcnt vmcnt(0)" ::: "memory")
#define POSTBAR() __builtin_amdgcn_s_barrier()

#define EIGHT_PHASE_LOOP(NI, KT0, LDB)                              \
  STAGE8(0, (KT0), LDB);                                            \
  VMDRAIN();                                                        \
  __builtin_amdgcn_s_barrier();                                     \
  for (int i = 0; i < (NI); ++i) {                                  \
    RDA(0, 0); RDB(0, 0);                                           \
    STAGE8(1, (KT0) + 2 * i + 1, LDB);                              \
    BARLG(); MMA(0, 0); POSTBAR();                                  \
    RDB(0, 1);                                                      \
    BARLG(); MMA(0, 1); POSTBAR();                                  \
    RDA(0, 1);                                                      \
    BARLG(); MMA(1, 1); POSTBAR();                                  \
    RDB(0, 0);                                                      \
    VMDRAIN();                                                      \
    BARLG(); MMA(1, 0); POSTBAR();                                  \
    RDA(1, 0); RDB(1, 0);                                           \
    if (i + 1 < (NI)) STAGE8(0, (KT0) + 2 * i + 2, LDB);            \
    BARLG(); MMA(0, 0); POSTBAR();                                  \
    RDB(1, 1);                                                      \
    BARLG(); MMA(0, 1); POSTBAR();                                  \
    RDA(1, 1);                                                      \
    BARLG(); MMA(1, 1); POSTBAR();                                  \
    RDB(1, 0);                                                      \
    if (i + 1 < (NI)) VMDRAIN();                                    \
    BARLG(); MMA(1, 0); POSTBAR();                                  \
  }

// ---------------- 256x256 8-phase: P = exp(q k^T) + rowsum partials (R3-verified) ----------------
__global__ __launch_bounds__(512, 2) void qk_exp_8ph(
    const unsigned short* __restrict__ A,   // qb [N][D]
    const unsigned short* __restrict__ B,   // kb [N][D]
    unsigned short* __restrict__ P,
    float* __restrict__ lpart) {
  __shared__ unsigned short Ash[2][256 * 64];
  __shared__ unsigned short Bsh[2][256 * 64];

  const int t = threadIdx.x;
  const int w = t >> 6, lane = t & 63;
  const int bid = blockIdx.x;
  const int swz = (bid & 7) * 128 + (bid >> 3);  // 1024 WGs, bijective
  const int tm = swz >> 5, tn = swz & 31;
  const int row0 = tm * 256, col0 = tn * 256;

  const int wr = w >> 2, wc = w & 3;
  const int l15 = lane & 15, lhi = lane >> 4, lx = lane & 7;

  const int sr = t >> 3;
  const int ss = ((t & 7) ^ (sr & 7)) * 8;
  const unsigned short* Ab = A + (size_t)(row0 + sr) * D + ss;
  const unsigned short* Bb = B + (size_t)(col0 + sr) * D + ss;
  const int ldst = t * 8;

  const int aRowB = (wr * 128 + l15) * 64;
  const int bRowB = (wc * 64 + l15) * 64;
  const int sl0 = ((0 + lhi) ^ lx) * 8;
  const int sl1 = ((4 + lhi) ^ lx) * 8;

  f32x4 acc[8][4] = {};
  short8 af[4][2], bf[2][2];

  EIGHT_PHASE_LOOP(4, 0, D)

  // epilogue: exp -> bf16 P + deterministic rowsum partials
#pragma unroll
  for (int fm = 0; fm < 8; ++fm) {
    const int r = row0 + wr * 128 + fm * 16 + lhi * 4;
    float rs[4] = {0.f, 0.f, 0.f, 0.f};
#pragma unroll
    for (int fn = 0; fn < 4; ++fn) {
      const int c = col0 + wc * 64 + fn * 16 + l15;
      f32x4 v = acc[fm][fn];
#pragma unroll
      for (int g = 0; g < 4; ++g) {
        unsigned short us = f2bf(__expf(v[g]));
        P[(size_t)(r + g) * N + c] = us;
        rs[g] += bf2f(us);
      }
    }
#pragma unroll
    for (int g = 0; g < 4; ++g) {
      float s = rs[g];
      s += __shfl_xor(s, 1);
      s += __shfl_xor(s, 2);
      s += __shfl_xor(s, 4);
      s += __shfl_xor(s, 8);
      if (l15 == 0) lpart[(size_t)(tn * 4 + wc) * N + r + g] = s;
    }
  }
}

// ---------------- 256x256 8-phase split-K PV: Opart[sp] = P[:,chunk] @ vT[:,chunk]^T ----------------
// 64 output tiles (32 tm x 2 tn) x 4 K-splits (2048 each) = 256 WGs = 1/CU.
// Partials 0..2 bf16; partial 3 f32 directly into d_out (reduce_k RMWs).
__global__ __launch_bounds__(512, 2) void pv_8ph(
    const unsigned short* __restrict__ A,   // P [N][N]
    const unsigned short* __restrict__ B,   // vT [D][N]
    unsigned short* __restrict__ Opart,
    float* __restrict__ outF) {
  __shared__ unsigned short Ash[2][256 * 64];
  __shared__ unsigned short Bsh[2][256 * 64];

  const int t = threadIdx.x;
  const int w = t >> 6, lane = t & 63;
  const int bid = blockIdx.x;
  const int swz = (bid & 7) * 32 + (bid >> 3);  // 256 WGs, bijective
  const int sp = swz >> 6;                       // 4 K-splits
  const int idx = swz & 63;
  const int tm = idx >> 1, tn = idx & 1;
  const int row0 = tm * 256, col0 = tn * 256;
  const int kt0 = sp * 32;                       // 32 K-tiles of 64 per split

  const int wr = w >> 2, wc = w & 3;
  const int l15 = lane & 15, lhi = lane >> 4, lx = lane & 7;

  const int sr = t >> 3;
  const int ss = ((t & 7) ^ (sr & 7)) * 8;
  const unsigned short* Ab = A + (size_t)(row0 + sr) * N + ss;
  const unsigned short* Bb = B + (size_t)(col0 + sr) * N + ss;
  const int ldst = t * 8;

  const int aRowB = (wr * 128 + l15) * 64;
  const int bRowB = (wc * 64 + l15) * 64;
  const int sl0 = ((0 + lhi) ^ lx) * 8;
  const int sl1 = ((4 + lhi) ^ lx) * 8;

  f32x4 acc[8][4] = {};
  short8 af[4][2], bf[2][2];

  EIGHT_PHASE_LOOP(16, kt0, N)

  // epilogue: write partial sp
  if (sp < 3) {
    unsigned short* op = Opart + (size_t)sp * ((size_t)N * D);
#pragma unroll
    for (int fm = 0; fm < 8; ++fm) {
      const int r = row0 + wr * 128 + fm * 16 + lhi * 4;
#pragma unroll
      for (int fn = 0; fn < 4; ++fn) {
        const int c = col0 + wc * 64 + fn * 16 + l15;
        f32x4 v = acc[fm][fn];
#pragma unroll
        for (int g = 0; g < 4; ++g) op[(size_t)(r + g) * D + c] = f2bf(v[g]);
      }
    }
  } else {
#pragma unroll
    for (int fm = 0; fm < 8; ++fm) {
      const int r = row0 + wr * 128 + fm * 16 + lhi * 4;
#pragma unroll
      for (int fn = 0; fn < 4; ++fn) {
        const int c = col0 + wc * 64 + fn * 16 + l15;
        f32x4 v = acc[fm][fn];
#pragma unroll
        for (int g = 0; g < 4; ++g) outF[(size_t)(r + g) * D + c] = v[g];
      }
    }
  }
}

// linv[m] = 1 / sum_{128 slots} lpart[slot][m]
__global__ void linv_k(const float* __restrict__ lpart, float* __restrict__ linv) {
  const int m = blockIdx.x * 256 + threadIdx.x;
  float s = 0.f;
  for (int i = 0; i < 128; ++i) s += lpart[(size_t)i * N + m];
  linv[m] = 1.0f / s;
}

// out[m][d] = linv[m] * (sum_{s<3} Opart_bf16[s][m][d] + out_f32[m][d])
__global__ void reduce_k(const unsigned short* __restrict__ Opart,
                         const float* __restrict__ linv, float* __restrict__ out) {
  const int i = blockIdx.x * 256 + threadIdx.x;  // over N*D/4
  const int m = i >> 7;                           // 128 float4 per row
  const float li = linv[m];
  const size_t nd = (size_t)N * D;
  ushort4 a = ((const ushort4*)Opart)[i];
  ushort4 b = ((const ushort4*)(Opart + nd))[i];
  ushort4 c = ((const ushort4*)(Opart + 2 * nd))[i];
  float4 o = ((float4*)out)[i];
  o.x = (bf2f(a.x) + bf2f(b.x) + bf2f(c.x) + o.x) * li;
  o.y = (bf2f(a.y) + bf2f(b.y) + bf2f(c.y) + o.y) * li;
  o.z = (bf2f(a.z) + bf2f(b.z) + bf2f(c.z) + o.z) * li;
  o.w = (bf2f(a.w) + bf2f(b.w) + bf2f(c.w) + o.w) * li;
  ((float4*)out)[i] = o;
}

extern "C" void kernel_launch(void* const* d_in, const int* in_sizes, int n_in,
                              void* d_out, int out_size, void* d_ws, size_t ws_size,
                              hipStream_t stream) {
  const float* z  = (const float*)d_in[0];
  const float* Wq = (const float*)d_in[1];
  const float* bq = (const float*)d_in[2];
  const float* Wk = (const float*)d_in[3];
  const float* bk = (const float*)d_in[4];
  const float* Wv = (const float*)d_in[5];
  const float* bv = (const float*)d_in[6];
  float* out = (float*)d_out;

  char* ws = (char*)d_ws;
  unsigned short* zb = (unsigned short*)(ws + 0);          //  8 MB  z bf16
  unsigned short* qb = (unsigned short*)(ws + 8388608);    //  8 MB  q bf16 (scaled)
  unsigned short* kb = (unsigned short*)(ws + 16777216);   //  8 MB  k bf16
  unsigned short* vT = (unsigned short*)(ws + 25165824);   //  8 MB  v^T bf16 [512][8192]
  unsigned short* wb = (unsigned short*)(ws + 33554432);   //  1.5MB W_qkv bf16 [1536][512]
  float* linv       = (float*)(ws + 33554432);             //  32 KB (overlays wb; wb dead after proj)
  float* bqkv       = (float*)(ws + 35127296);             //  6 KB  biases f32
  float* lpart      = (float*)(ws + 35133440);             //  4 MB  rowsum partials [128][8192]
  unsigned short* P = (unsigned short*)(ws + 39327744);    // 128 MB P bf16 [8192][8192]
  // Opart partials 0..2 overlay zb/qb/kb (dead by PV); partial 3 -> d_out f32
  unsigned short* Opart = (unsigned short*)(ws + 0);

  cast_z_k<<<dim3(2048), dim3(256), 0, stream>>>(z, zb);
  cast_w_k<<<dim3(768), dim3(256), 0, stream>>>(Wq, Wk, Wv, bq, bk, bv, wb, bqkv);

  // qkv projection: [8192x1536] = zb @ wb^T (+bias)
  proj_qkv<<<dim3(768), dim3(256), 0, stream>>>(zb, wb, bqkv, qb, kb, vT);

  // scores+exp: P = exp(qb @ kb^T), 256x256 8-phase
  qk_exp_8ph<<<dim3(1024), dim3(512), 0, stream>>>(qb, kb, P, lpart);

  // row-sum inverse
  linv_k<<<dim3(32), dim3(256), 0, stream>>>(lpart, linv);

  // split-K PV (4 splits x K=2048), 256x256 8-phase
  pv_8ph<<<dim3(256), dim3(512), 0, stream>>>(P, vT, Opart, out);

  // out = linv * (sum partials + d_out partial)
  reduce_k<<<dim3(4096), dim3(256), 0, stream>>>(Opart, linv, out);
}